// Round 2
// baseline (882.684 us; speedup 1.0000x reference)
//
#include <hip/hip_runtime.h>

// FlowNetC correlation on MI355X (round 2).
// out[b, dyi*21+dxi, y, x] = (1/128) * sum_c in1[b,c,y,x] * in2[b,c,y+dy,x+dx]
//   dy = 2*(dyi-10), dx = 2*(dxi-10); in2 zero outside [0,96)^2.
//
// R2 changes vs R1 (LDS-pipe-bound, 2e7 bank conflicts, 16% occupancy):
//  - GX=8: v-traffic 1.14 -> 0.67 B/FMA (LDS reads 2.77 -> 1.78 GB)
//  - lds1 per-parity row padded 48 -> 52 (unit stride 104 % 128B spreads banks;
//    48 gave stride 96 = 0 mod 32 banks -> 8-way conflicts on reads AND writes)
//  - staging writes as float2 (parity pairs are contiguous) -> half the writes
//  - TY=16 rows/block, CC=4 channels/chunk -> 60 KB LDS, 2 blocks/CU

#define BB 4
#define CC_ALL 128
#define HH 96
#define WW 96
#define ND 21
#define TY 16           // rows per block
#define CCH 4           // channels per chunk
#define NCHUNK (CC_ALL / CCH)   // 32
#define GX 8            // x-positions (one parity) per thread
#define NTHR 192        // 16 rows * 12 (6 u-units * 2 parities)
#define L1P 52          // padded per-parity in1 row (48 used)
#define L1U (2 * L1P)   // 104 floats per (c,row)
#define W2P 68          // per-parity in2 row: X in [-20,116) -> 68
#define L2U (2 * W2P)   // 136 floats per (c,row)

__global__ __launch_bounds__(NTHR, 2)
void corr_kernel(const float* __restrict__ in1,
                 const float* __restrict__ in2,
                 float* __restrict__ out) {
    __shared__ float lds1[CCH * TY * L1U];   // 6656 f = 26 KB
    __shared__ float lds2[CCH * TY * L2U];   // 8704 f = 34 KB

    const int tid = threadIdx.x;
    const int y0  = blockIdx.x * TY;
    const int dyi = blockIdx.y;            // 0..20
    const int b   = blockIdx.z;
    const int dy  = 2 * (dyi - 10);

    // compute-phase mapping: 12 threads per row = 2 parities x 6 units of GX=8
    const int r   = tid / 12;              // 0..15
    const int un_ = tid % 12;
    const int p   = un_ / 6;               // parity
    const int u0  = (un_ % 6) * GX;        // 0,8,...,40

    float acc[ND * GX];
#pragma unroll
    for (int i = 0; i < ND * GX; ++i) acc[i] = 0.f;

    const float* in1b = in1 + b * (CC_ALL * HH * WW);
    const float* in2b = in2 + b * (CC_ALL * HH * WW);

    // one-time zero fill of lds2: borders (X<0 or X>=96) and out-of-range rows
    // stay zero for every chunk (never overwritten).
    {
        float4 z = make_float4(0.f, 0.f, 0.f, 0.f);
        for (int k = tid; k < (CCH * TY * L2U) / 4; k += NTHR)
            ((float4*)lds2)[k] = z;
    }

    for (int ch = 0; ch < NCHUNK; ++ch) {
        const int c0 = ch * CCH;
        __syncthreads();   // covers zero-init (first iter) / prior compute reads

        // ---- stage in1 chunk: CCH*TY rows of 96 floats, float4 in / float2 out
        // f = tid + k*NTHR in [0,1536): x4 = f%24, rc = f/24, c = rc>>4, rr = rc&15
#pragma unroll
        for (int k = 0; k < 8; ++k) {
            int f  = tid + k * NTHR;
            int x4 = f % 24;
            int rc = f / 24;
            int c  = rc >> 4, rr = rc & 15;
            const float4 g = *(const float4*)&in1b[(c0 + c) * (HH * WW) + (y0 + rr) * WW + x4 * 4];
            float* base = &lds1[(c * TY + rr) * L1U];
            // x = 4*x4 + j; even x -> idx x/2, odd x -> idx (x-1)/2, in parity arrays
            *(float2*)&base[      2 * x4] = make_float2(g.x, g.z);
            *(float2*)&base[L1P + 2 * x4] = make_float2(g.y, g.w);
        }

        // ---- stage in2 chunk interior (X in [0,96)), rows y0+rr+dy ----
#pragma unroll
        for (int k = 0; k < 8; ++k) {
            int f  = tid + k * NTHR;
            int x4 = f % 24;
            int rc = f / 24;
            int c  = rc >> 4, rr = rc & 15;
            int Y  = y0 + rr + dy;
            if ((unsigned)Y < HH) {
                const float4 g = *(const float4*)&in2b[(c0 + c) * (HH * WW) + Y * WW + x4 * 4];
                float* base = &lds2[(c * TY + rr) * L2U];
                // X = 4*x4 + j; even: idx X/2+10, odd: idx (X-1)/2+10
                *(float2*)&base[      2 * x4 + 10] = make_float2(g.x, g.z);
                *(float2*)&base[W2P + 2 * x4 + 10] = make_float2(g.y, g.w);
            }
        }
        __syncthreads();

        // ---- compute: per channel, 2 b128 (af) + 7 b128 (v) feed 168 FMAs ----
#pragma unroll
        for (int c = 0; c < CCH; ++c) {
            const float* a8  = &lds1[(c * TY + r) * L1U + p * L1P + u0];
            const float* v28 = &lds2[(c * TY + r) * L2U + p * W2P + u0];
            float a[GX];
            {
                float4 t0 = *(const float4*)&a8[0];
                float4 t1 = *(const float4*)&a8[4];
                a[0] = t0.x; a[1] = t0.y; a[2] = t0.z; a[3] = t0.w;
                a[4] = t1.x; a[5] = t1.y; a[6] = t1.z; a[7] = t1.w;
            }
            float v[GX + 20];
#pragma unroll
            for (int m = 0; m < GX + 20; m += 4) {
                float4 t = *(const float4*)&v28[m];
                v[m] = t.x; v[m + 1] = t.y; v[m + 2] = t.z; v[m + 3] = t.w;
            }
#pragma unroll
            for (int id = 0; id < ND; ++id) {
#pragma unroll
                for (int j = 0; j < GX; ++j) {
                    acc[id * GX + j] += a[j] * v[id + j];
                }
            }
        }
    }

    // ---- epilogue: scale and write ----
    const float scale = 1.0f / 128.0f;
#pragma unroll
    for (int id = 0; id < ND; ++id) {
        int d = dyi * ND + id;
        int base = ((b * (ND * ND) + d) * HH + (y0 + r)) * WW;
#pragma unroll
        for (int j = 0; j < GX; ++j) {
            int x = 2 * (u0 + j) + p;
            out[base + x] = acc[id * GX + j] * scale;
        }
    }
}

extern "C" void kernel_launch(void* const* d_in, const int* in_sizes, int n_in,
                              void* d_out, int out_size, void* d_ws, size_t ws_size,
                              hipStream_t stream) {
    const float* in1 = (const float*)d_in[0];
    const float* in2 = (const float*)d_in[1];
    float* out = (float*)d_out;
    dim3 grid(HH / TY, ND, BB);
    dim3 block(NTHR);
    hipLaunchKernelGGL(corr_kernel, grid, block, 0, stream, in1, in2, out);
}

// Round 3
// 222.433 us; speedup vs baseline: 3.9683x; 3.9683x over previous
//
#include <hip/hip_runtime.h>

// FlowNetC correlation on MI355X (round 3).
// out[b, dyi*21+dxi, y, x] = (1/128) * sum_c in1[b,c,y,x] * in2[b,c,y+dy,x+dx]
//   dy = 2*(dyi-10), dx = 2*(dxi-10); in2 zero outside [0,96)^2.
//
// R3 = R1's register shape (GX=4, 84 accs, 128 VGPRs, no spills) with:
//  - lds1 per-parity row padded 48 -> 52: unit stride 104 = 8 mod 32 banks
//    (R1's 96 = 0 mod 32 caused the 2.05e7 bank-conflict cycles)
//  - CCH=4 channels/chunk -> 30 KB LDS -> 5 blocks/CU (R1: 59 KB -> 2)
//  - float2 parity-pair staging writes (half the write instructions)
// R2's GX=8 spilled (168 accs > 128 VGPRs -> 2.1 GB scratch traffic). Don't.

#define BB 4
#define CC_ALL 128
#define HH 96
#define WW 96
#define ND 21
#define TY 8            // rows per block
#define CCH 4           // channels per chunk
#define NCHUNK (CC_ALL / CCH)   // 32
#define GX 4            // x-positions (one parity) per thread
#define NTHR 192        // 8 rows * 24 (12 u-units * 2 parities)
#define L1P 52          // padded per-parity in1 row (48 used)
#define L1U (2 * L1P)   // 104 floats per (c,row); 104 % 32 == 8
#define W2P 68          // per-parity in2 row: X in [-20,116) -> 68
#define L2U (2 * W2P)   // 136 floats per (c,row); 136 % 32 == 8

__global__ __launch_bounds__(NTHR, 2)
void corr_kernel(const float* __restrict__ in1,
                 const float* __restrict__ in2,
                 float* __restrict__ out) {
    __shared__ float lds1[CCH * TY * L1U];   // 3328 f = 13 KB
    __shared__ float lds2[CCH * TY * L2U];   // 4352 f = 17 KB

    const int tid = threadIdx.x;
    const int y0  = blockIdx.x * TY;
    const int dyi = blockIdx.y;            // 0..20
    const int b   = blockIdx.z;
    const int dy  = 2 * (dyi - 10);

    // compute-phase mapping: 24 threads/row = 2 parities x 12 units of GX=4
    const int r   = tid / 24;              // 0..7
    const int un_ = tid % 24;
    const int p   = un_ / 12;              // parity
    const int u0  = (un_ % 12) * GX;       // 0,4,...,44

    float acc[ND * GX];
#pragma unroll
    for (int i = 0; i < ND * GX; ++i) acc[i] = 0.f;

    const float* in1b = in1 + b * (CC_ALL * HH * WW);
    const float* in2b = in2 + b * (CC_ALL * HH * WW);

    // one-time zero fill of lds2: borders (X<0 or X>=96) and out-of-range rows
    // stay zero for every chunk (never overwritten).
    {
        float4 z = make_float4(0.f, 0.f, 0.f, 0.f);
        for (int k = tid; k < (CCH * TY * L2U) / 4; k += NTHR)
            ((float4*)lds2)[k] = z;
    }

    for (int ch = 0; ch < NCHUNK; ++ch) {
        const int c0 = ch * CCH;
        __syncthreads();   // covers zero-init (first iter) / prior compute reads

        // ---- stage in1 chunk: CCH*TY rows of 96 floats, float4 in / float2 out
        // f = tid + k*NTHR in [0,768): x4 = f%24, rc = f/24, c = rc>>3, rr = rc&7
#pragma unroll
        for (int k = 0; k < 4; ++k) {
            int f  = tid + k * NTHR;
            int x4 = f % 24;
            int rc = f / 24;
            int c  = rc >> 3, rr = rc & 7;
            const float4 g = *(const float4*)&in1b[(c0 + c) * (HH * WW) + (y0 + rr) * WW + x4 * 4];
            float* base = &lds1[(c * TY + rr) * L1U];
            // x = 4*x4 + j; even x -> idx x/2, odd x -> idx (x-1)/2, per parity
            *(float2*)&base[      2 * x4] = make_float2(g.x, g.z);
            *(float2*)&base[L1P + 2 * x4] = make_float2(g.y, g.w);
        }

        // ---- stage in2 chunk interior (X in [0,96)), rows y0+rr+dy ----
#pragma unroll
        for (int k = 0; k < 4; ++k) {
            int f  = tid + k * NTHR;
            int x4 = f % 24;
            int rc = f / 24;
            int c  = rc >> 3, rr = rc & 7;
            int Y  = y0 + rr + dy;
            if ((unsigned)Y < HH) {
                const float4 g = *(const float4*)&in2b[(c0 + c) * (HH * WW) + Y * WW + x4 * 4];
                float* base = &lds2[(c * TY + rr) * L2U];
                // X = 4*x4 + j; even: idx X/2+10, odd: idx (X-1)/2+10
                *(float2*)&base[      2 * x4 + 10] = make_float2(g.x, g.z);
                *(float2*)&base[W2P + 2 * x4 + 10] = make_float2(g.y, g.w);
            }
        }
        __syncthreads();

        // ---- compute: per channel, 1 b128 (a) + 6 b128 (v) feed 84 FMAs ----
#pragma unroll
        for (int c = 0; c < CCH; ++c) {
            const float* a4  = &lds1[(c * TY + r) * L1U + p * L1P + u0];
            const float* v24 = &lds2[(c * TY + r) * L2U + p * W2P + u0];
            float4 af = *(const float4*)a4;
            float v[24];
#pragma unroll
            for (int m = 0; m < 24; m += 4) {
                float4 t = *(const float4*)&v24[m];
                v[m] = t.x; v[m + 1] = t.y; v[m + 2] = t.z; v[m + 3] = t.w;
            }
#pragma unroll
            for (int id = 0; id < ND; ++id) {
                acc[id * GX + 0] += af.x * v[id + 0];
                acc[id * GX + 1] += af.y * v[id + 1];
                acc[id * GX + 2] += af.z * v[id + 2];
                acc[id * GX + 3] += af.w * v[id + 3];
            }
        }
    }

    // ---- epilogue: scale and write ----
    const float scale = 1.0f / 128.0f;
#pragma unroll
    for (int id = 0; id < ND; ++id) {
        int d = dyi * ND + id;
        int base = ((b * (ND * ND) + d) * HH + (y0 + r)) * WW;
#pragma unroll
        for (int j = 0; j < GX; ++j) {
            int x = 2 * (u0 + j) + p;
            out[base + x] = acc[id * GX + j] * scale;
        }
    }
}

extern "C" void kernel_launch(void* const* d_in, const int* in_sizes, int n_in,
                              void* d_out, int out_size, void* d_ws, size_t ws_size,
                              hipStream_t stream) {
    const float* in1 = (const float*)d_in[0];
    const float* in2 = (const float*)d_in[1];
    float* out = (float*)d_out;
    dim3 grid(HH / TY, ND, BB);
    dim3 block(NTHR);
    hipLaunchKernelGGL(corr_kernel, grid, block, 0, stream, in1, in2, out);
}

// Round 4
// 123.432 us; speedup vs baseline: 7.1511x; 1.8021x over previous
//
#include <hip/hip_runtime.h>

// FlowNetC correlation on MI355X (round 4): MFMA banded-correlation.
// out[b, dyi*21+dxi, y, x] = (1/128) * sum_c in1[b,c,y,x] * in2[b,c,y+dy,x+dx]
//   dy = 2*(dyi-10), dx = 2*(dxi-10); in2 zero outside [0,96)^2.
//
// Parity split x = 2*xi + p  =>  out[xi, dxi] = sum_c A[xi,c] * B[xi+dxi-10, c]
// = width-21 band of A·B^T per (b, y, dy, p). Tiled 16x16x32 bf16 MFMA:
// M-tiles xi in {0,16,32}, N-tiles xi' in {0,16,32}; 7 tile pairs carry the
// band; out-of-range band entries are exactly zero (skipped tiles).
//
// Pre-pass: transpose+cvt inputs to bf16 T[b][y][p][kq(16)][xi(48)][8c] in d_ws
// so MFMA frags are direct 16B/lane global gathers (K-contiguous). No LDS in
// the K-loop (wave=row => zero cross-wave frag reuse). Epilogue: C-tiles ->
// per-wave LDS [d][x] -> coalesced float4 stores.
// Fallback to the R3 VALU kernel if ws_size < 18.9 MB.

#define BB 4
#define CC_ALL 128
#define HH 96
#define WW 96
#define ND 21

typedef __attribute__((ext_vector_type(8))) short short8;
typedef __attribute__((ext_vector_type(4))) float floatx4;

// ---------------- pre-pass: f32 [b][c][y][x] -> bf16 [b][y][p][kq][xi][8c] ---
// thread g = (b, y, kq, xi): loads 8 float2 (c = 8kq..8kq+7, x = 2xi..2xi+1),
// RNE-converts, writes one 16B group per parity. Loads: 48 consecutive-xi
// lanes = 384 contiguous bytes. Stores: consecutive lanes -> consecutive 16B.
__global__ __launch_bounds__(256)
void transpose_cvt(const float* __restrict__ src, ushort* __restrict__ dst) {
    int g  = blockIdx.x * 256 + threadIdx.x;        // < 4*96*16*48 = 294912
    int xi = g % 48;
    int t1 = g / 48;
    int kq = t1 % 16;
    int t2 = t1 / 16;
    int y  = t2 % 96;
    int b  = t2 / 96;

    const float* s = src + (((b * CC_ALL + kq * 8) * HH + y) * WW) + 2 * xi;
    ushort e[8], o[8];
#pragma unroll
    for (int j = 0; j < 8; ++j) {
        float2 f = *(const float2*)(s + j * (HH * WW));
        unsigned ue = __builtin_bit_cast(unsigned, f.x);
        unsigned uo = __builtin_bit_cast(unsigned, f.y);
        e[j] = (ushort)((ue + 0x7FFFu + ((ue >> 16) & 1u)) >> 16);
        o[j] = (ushort)((uo + 0x7FFFu + ((uo >> 16) & 1u)) >> 16);
    }
    // dst group index (b,y,p,kq,xi): (((b*96+y)*2+p)*16+kq)*48+xi, 8 ushorts per group
    int base = (((b * 96 + y) * 2 + 0) * 16 + kq) * 48 + xi;
    uint4 we, wo;
    we.x = e[0] | ((unsigned)e[1] << 16); we.y = e[2] | ((unsigned)e[3] << 16);
    we.z = e[4] | ((unsigned)e[5] << 16); we.w = e[6] | ((unsigned)e[7] << 16);
    wo.x = o[0] | ((unsigned)o[1] << 16); wo.y = o[2] | ((unsigned)o[3] << 16);
    wo.z = o[4] | ((unsigned)o[5] << 16); wo.w = o[6] | ((unsigned)o[7] << 16);
    *(uint4*)(dst + base * 8)            = we;   // p = 0
    *(uint4*)(dst + (base + 16 * 48) * 8) = wo;  // p = 1 (+6144 ushorts)
}

// ---------------- main: banded MFMA correlation ------------------------------
// grid (24 y-tiles, 21 dyi, 4 b), block 256 = 4 waves, wave w = row y0+w.
__global__ __launch_bounds__(256)
void corr_mfma(const ushort* __restrict__ T1, const ushort* __restrict__ T2,
               float* __restrict__ out) {
    __shared__ float lds[4 * ND * 100];   // per-wave [21 d][96 x (+4 pad)]

    const int tid  = threadIdx.x;
    const int w    = tid >> 6;
    const int lane = tid & 63;
    const int n    = lane & 15;           // N index / A's M index
    const int q    = lane >> 4;           // quad
    const int yt   = blockIdx.x;
    const int dyi  = blockIdx.y;
    const int b    = blockIdx.z;
    const int y    = yt * 4 + w;
    const int dy   = 2 * (dyi - 10);
    const int Y2   = y + dy;
    const bool rowok = (unsigned)Y2 < (unsigned)HH;

    // 7 (M-tile, N-tile) band pairs per parity
    const int TS_t[7] = {0, 0, 1, 1, 1, 2, 2};
    const int TS_s[7] = {0, 1, 0, 1, 2, 1, 2};

    floatx4 acc[14];
#pragma unroll
    for (int i = 0; i < 14; ++i) acc[i] = (floatx4)(0.0f);

    // per-(b,y,p) block = 16*48*8 = 6144 ushorts
    const ushort* A0 = T1 + ((b * 96 + y) * 2) * 6144;

    if (rowok) {
        const ushort* B0 = T2 + ((b * 96 + Y2) * 2) * 6144;
        for (int ch = 0; ch < 4; ++ch) {          // K chunks of 32 channels
            const int kofs = (4 * ch + q) * 384 + n * 8;   // (kq)*48*8 + xi*8
#pragma unroll
            for (int p = 0; p < 2; ++p) {
                const ushort* Ab = A0 + p * 6144 + kofs;
                const ushort* Bb = B0 + p * 6144 + kofs;
                short8 af0 = *(const short8*)(Ab);
                short8 af1 = *(const short8*)(Ab + 128);   // +16 xi
                short8 af2 = *(const short8*)(Ab + 256);   // +32 xi
                short8 bf0 = *(const short8*)(Bb);
                short8 bf1 = *(const short8*)(Bb + 128);
                short8 bf2 = *(const short8*)(Bb + 256);
                acc[p*7+0] = __builtin_amdgcn_mfma_f32_16x16x32_bf16(af0, bf0, acc[p*7+0], 0, 0, 0);
                acc[p*7+1] = __builtin_amdgcn_mfma_f32_16x16x32_bf16(af0, bf1, acc[p*7+1], 0, 0, 0);
                acc[p*7+2] = __builtin_amdgcn_mfma_f32_16x16x32_bf16(af1, bf0, acc[p*7+2], 0, 0, 0);
                acc[p*7+3] = __builtin_amdgcn_mfma_f32_16x16x32_bf16(af1, bf1, acc[p*7+3], 0, 0, 0);
                acc[p*7+4] = __builtin_amdgcn_mfma_f32_16x16x32_bf16(af1, bf2, acc[p*7+4], 0, 0, 0);
                acc[p*7+5] = __builtin_amdgcn_mfma_f32_16x16x32_bf16(af2, bf1, acc[p*7+5], 0, 0, 0);
                acc[p*7+6] = __builtin_amdgcn_mfma_f32_16x16x32_bf16(af2, bf2, acc[p*7+6], 0, 0, 0);
            }
        }
    }

    // ---- epilogue: C-tiles -> per-wave LDS [d][x] -> coalesced stores ----
    float* wl = lds + w * (ND * 100);
    {
        float4 z = make_float4(0.f, 0.f, 0.f, 0.f);
        for (int k = lane; k < (ND * 100) / 4; k += 64) ((float4*)wl)[k] = z;
    }
    const float scale = 1.0f / 128.0f;
#pragma unroll
    for (int p = 0; p < 2; ++p) {
#pragma unroll
        for (int i = 0; i < 7; ++i) {
            const int t = TS_t[i], s = TS_s[i];
#pragma unroll
            for (int r = 0; r < 4; ++r) {
                // D[m][n]: row m = q*4+r, col = n  (m89/m91-verified mapping)
                int m = q * 4 + r;
                int d = 16 * s + n - 16 * t - m + 10;   // dxi
                int x = 2 * (16 * t + m) + p;
                if (0 <= d && d <= 20)
                    wl[d * 100 + x] = acc[p * 7 + i][r] * scale;
            }
        }
    }
    // same-wave LDS RAW: compiler inserts lgkmcnt waits; no barrier needed.
    const int base0 = ((b * (ND * ND) + dyi * ND) * HH + y) * WW;
#pragma unroll
    for (int i = 0; i < 8; ++i) {
        int fl = i * 64 + lane;               // float4 index, 21*24 = 504 total
        if (fl < 504) {
            int d  = fl / 24;
            int xi = fl % 24;
            float4 v = *(const float4*)(wl + d * 100 + xi * 4);
            *(float4*)(out + base0 + d * (HH * WW) + xi * 4) = v;
        }
    }
}

// ---------------- fallback (R3 VALU kernel) if ws too small ------------------
#define TY 8
#define CCH 4
#define NCHUNK (CC_ALL / CCH)
#define GX 4
#define NTHR 192
#define L1P 52
#define L1U (2 * L1P)
#define W2P 68
#define L2U (2 * W2P)

__global__ __launch_bounds__(NTHR, 2)
void corr_kernel(const float* __restrict__ in1,
                 const float* __restrict__ in2,
                 float* __restrict__ out) {
    __shared__ float lds1[CCH * TY * L1U];
    __shared__ float lds2[CCH * TY * L2U];
    const int tid = threadIdx.x;
    const int y0  = blockIdx.x * TY;
    const int dyi = blockIdx.y;
    const int b   = blockIdx.z;
    const int dy  = 2 * (dyi - 10);
    const int r   = tid / 24;
    const int un_ = tid % 24;
    const int p   = un_ / 12;
    const int u0  = (un_ % 12) * GX;
    float acc[ND * GX];
#pragma unroll
    for (int i = 0; i < ND * GX; ++i) acc[i] = 0.f;
    const float* in1b = in1 + b * (CC_ALL * HH * WW);
    const float* in2b = in2 + b * (CC_ALL * HH * WW);
    {
        float4 z = make_float4(0.f, 0.f, 0.f, 0.f);
        for (int k = tid; k < (CCH * TY * L2U) / 4; k += NTHR)
            ((float4*)lds2)[k] = z;
    }
    for (int ch = 0; ch < NCHUNK; ++ch) {
        const int c0 = ch * CCH;
        __syncthreads();
#pragma unroll
        for (int k = 0; k < 4; ++k) {
            int f  = tid + k * NTHR;
            int x4 = f % 24;
            int rc = f / 24;
            int c  = rc >> 3, rr = rc & 7;
            const float4 g = *(const float4*)&in1b[(c0 + c) * (HH * WW) + (y0 + rr) * WW + x4 * 4];
            float* base = &lds1[(c * TY + rr) * L1U];
            *(float2*)&base[      2 * x4] = make_float2(g.x, g.z);
            *(float2*)&base[L1P + 2 * x4] = make_float2(g.y, g.w);
        }
#pragma unroll
        for (int k = 0; k < 4; ++k) {
            int f  = tid + k * NTHR;
            int x4 = f % 24;
            int rc = f / 24;
            int c  = rc >> 3, rr = rc & 7;
            int Y  = y0 + rr + dy;
            if ((unsigned)Y < HH) {
                const float4 g = *(const float4*)&in2b[(c0 + c) * (HH * WW) + Y * WW + x4 * 4];
                float* base = &lds2[(c * TY + rr) * L2U];
                *(float2*)&base[      2 * x4 + 10] = make_float2(g.x, g.z);
                *(float2*)&base[W2P + 2 * x4 + 10] = make_float2(g.y, g.w);
            }
        }
        __syncthreads();
#pragma unroll
        for (int c = 0; c < CCH; ++c) {
            const float* a4  = &lds1[(c * TY + r) * L1U + p * L1P + u0];
            const float* v24 = &lds2[(c * TY + r) * L2U + p * W2P + u0];
            float4 af = *(const float4*)a4;
            float v[24];
#pragma unroll
            for (int m = 0; m < 24; m += 4) {
                float4 t = *(const float4*)&v24[m];
                v[m] = t.x; v[m + 1] = t.y; v[m + 2] = t.z; v[m + 3] = t.w;
            }
#pragma unroll
            for (int id = 0; id < ND; ++id) {
                acc[id * GX + 0] += af.x * v[id + 0];
                acc[id * GX + 1] += af.y * v[id + 1];
                acc[id * GX + 2] += af.z * v[id + 2];
                acc[id * GX + 3] += af.w * v[id + 3];
            }
        }
    }
    const float scale = 1.0f / 128.0f;
#pragma unroll
    for (int id = 0; id < ND; ++id) {
        int d = dyi * ND + id;
        int base = ((b * (ND * ND) + d) * HH + (y0 + r)) * WW;
#pragma unroll
        for (int j = 0; j < GX; ++j) {
            int x = 2 * (u0 + j) + p;
            out[base + x] = acc[id * GX + j] * scale;
        }
    }
}

extern "C" void kernel_launch(void* const* d_in, const int* in_sizes, int n_in,
                              void* d_out, int out_size, void* d_ws, size_t ws_size,
                              hipStream_t stream) {
    const float* in1 = (const float*)d_in[0];
    const float* in2 = (const float*)d_in[1];
    float* out = (float*)d_out;
    const size_t elems = (size_t)BB * CC_ALL * HH * WW;      // 4,718,592 per tensor
    const size_t need  = 2 * elems * sizeof(ushort);         // 18,874,368 B

    if (ws_size >= need) {
        ushort* T1 = (ushort*)d_ws;
        ushort* T2 = T1 + elems;
        dim3 tg(294912 / 256);   // 1152 blocks
        hipLaunchKernelGGL(transpose_cvt, tg, dim3(256), 0, stream, in1, T1);
        hipLaunchKernelGGL(transpose_cvt, tg, dim3(256), 0, stream, in2, T2);
        dim3 grid(HH / 4, ND, BB);
        hipLaunchKernelGGL(corr_mfma, grid, dim3(256), 0, stream, T1, T2, out);
    } else {
        dim3 grid(HH / TY, ND, BB);
        hipLaunchKernelGGL(corr_kernel, grid, dim3(NTHR), 0, stream, in1, in2, out);
    }
}

// Round 5
// 122.343 us; speedup vs baseline: 7.2149x; 1.0089x over previous
//
#include <hip/hip_runtime.h>

// FlowNetC correlation on MI355X (round 5): MFMA banded-correlation.
// out[b, dyi*21+dxi, y, x] = (1/128) * sum_c in1[b,c,y,x] * in2[b,c,y+dy,x+dx]
//   dy = 2*(dyi-10), dx = 2*(dxi-10); in2 zero outside [0,96)^2.
//
// Parity split x = 2*xi + p  =>  out[xi, dxi] = sum_c A[xi,c] * B[xi+dxi-10, c]
// = width-21 band of A·B^T per (b, y, dy, p). Tiled 16x16x32 bf16 MFMA.
//
// R5 vs R4 (123 us total, ~50 us of that is harness poison/restore):
//  - the two transpose_cvt launches fused into ONE kernel (grid.y = tensor)
//  - transpose loads widened float2 -> float4 (2 xi per thread), writes are
//    32 B contiguous per lane per parity (coalesced); half the threads
//  - the 1/128 output scale folded into in1's bf16 conversion (2^-7 exact in
//    bf16) -> corr epilogue loses 56 v_mul per wave
// corr_mfma band/layout logic unchanged (verified in R4).

#define BB 4
#define CC_ALL 128
#define HH 96
#define WW 96
#define ND 21

typedef __attribute__((ext_vector_type(8))) short short8;
typedef __attribute__((ext_vector_type(4))) float floatx4;

__device__ __forceinline__ ushort f2bf(float f) {
    unsigned u = __builtin_bit_cast(unsigned, f);
    return (ushort)((u + 0x7FFFu + ((u >> 16) & 1u)) >> 16);
}

// ---- pre-pass (fused): f32 [b][c][y][x] -> bf16 [b][y][p][kq(16)][xi(48)][8c]
// blockIdx.y selects tensor (0: in1, scaled by 1/128; 1: in2).
// thread g = (b, y, kq, t), t in [0,24): loads 8 float4 (c = 8kq..8kq+7,
// x = 4t..4t+3), converts, writes 32 B (2 xi-groups) per parity.
__global__ __launch_bounds__(256)
void transpose_cvt2(const float* __restrict__ in1, const float* __restrict__ in2,
                    ushort* __restrict__ T1, ushort* __restrict__ T2) {
    const int sel = blockIdx.y;
    const float* __restrict__ src = sel ? in2 : in1;
    ushort* __restrict__ dst = sel ? T2 : T1;
    const float mul = sel ? 1.0f : (1.0f / 128.0f);

    int g  = blockIdx.x * 256 + threadIdx.x;   // < 4*96*16*24 = 147456
    int t  = g % 24;
    int t1 = g / 24;
    int kq = t1 % 16;
    int t2 = t1 / 16;
    int y  = t2 % 96;
    int b  = t2 / 96;

    const float* s = src + (((b * CC_ALL + kq * 8) * HH + y) * WW) + 4 * t;
    ushort e0[8], e1[8], o0[8], o1[8];      // xi = 2t (0) and 2t+1 (1)
#pragma unroll
    for (int j = 0; j < 8; ++j) {
        float4 f = *(const float4*)(s + j * (HH * WW));
        e0[j] = f2bf(f.x * mul);            // x = 4t   -> even, xi = 2t
        o0[j] = f2bf(f.y * mul);            // x = 4t+1 -> odd,  xi = 2t
        e1[j] = f2bf(f.z * mul);            // x = 4t+2 -> even, xi = 2t+1
        o1[j] = f2bf(f.w * mul);            // x = 4t+3 -> odd,  xi = 2t+1
    }
    // group index (b,y,p,kq,xi) = (((b*96+y)*2+p)*16+kq)*48 + xi ; 8 ushort/group
    int base = (((b * 96 + y) * 2 + 0) * 16 + kq) * 48 + 2 * t;
    uint4 w;
    ushort* d0 = dst + base * 8;                 // parity 0
    w.x = e0[0] | ((unsigned)e0[1] << 16); w.y = e0[2] | ((unsigned)e0[3] << 16);
    w.z = e0[4] | ((unsigned)e0[5] << 16); w.w = e0[6] | ((unsigned)e0[7] << 16);
    *(uint4*)(d0) = w;
    w.x = e1[0] | ((unsigned)e1[1] << 16); w.y = e1[2] | ((unsigned)e1[3] << 16);
    w.z = e1[4] | ((unsigned)e1[5] << 16); w.w = e1[6] | ((unsigned)e1[7] << 16);
    *(uint4*)(d0 + 8) = w;
    ushort* d1 = d0 + 16 * 48 * 8;               // parity 1 (+6144 ushorts)
    w.x = o0[0] | ((unsigned)o0[1] << 16); w.y = o0[2] | ((unsigned)o0[3] << 16);
    w.z = o0[4] | ((unsigned)o0[5] << 16); w.w = o0[6] | ((unsigned)o0[7] << 16);
    *(uint4*)(d1) = w;
    w.x = o1[0] | ((unsigned)o1[1] << 16); w.y = o1[2] | ((unsigned)o1[3] << 16);
    w.z = o1[4] | ((unsigned)o1[5] << 16); w.w = o1[6] | ((unsigned)o1[7] << 16);
    *(uint4*)(d1 + 8) = w;
}

// ---------------- main: banded MFMA correlation ------------------------------
// grid (24 y-tiles, 21 dyi, 4 b), block 256 = 4 waves, wave w = row y0+w.
// Scale 1/128 is pre-folded into T1.
__global__ __launch_bounds__(256)
void corr_mfma(const ushort* __restrict__ T1, const ushort* __restrict__ T2,
               float* __restrict__ out) {
    __shared__ float lds[4 * ND * 100];   // per-wave [21 d][96 x (+4 pad)]

    const int tid  = threadIdx.x;
    const int w    = tid >> 6;
    const int lane = tid & 63;
    const int n    = lane & 15;           // N index / A's M index
    const int q    = lane >> 4;           // quad
    const int yt   = blockIdx.x;
    const int dyi  = blockIdx.y;
    const int b    = blockIdx.z;
    const int y    = yt * 4 + w;
    const int dy   = 2 * (dyi - 10);
    const int Y2   = y + dy;
    const bool rowok = (unsigned)Y2 < (unsigned)HH;

    // 7 (M-tile, N-tile) band pairs per parity
    const int TS_t[7] = {0, 0, 1, 1, 1, 2, 2};
    const int TS_s[7] = {0, 1, 0, 1, 2, 1, 2};

    floatx4 acc[14];
#pragma unroll
    for (int i = 0; i < 14; ++i) acc[i] = (floatx4)(0.0f);

    // per-(b,y,p) block = 16*48*8 = 6144 ushorts
    const ushort* A0 = T1 + ((b * 96 + y) * 2) * 6144;

    if (rowok) {
        const ushort* B0 = T2 + ((b * 96 + Y2) * 2) * 6144;
        for (int ch = 0; ch < 4; ++ch) {          // K chunks of 32 channels
            const int kofs = (4 * ch + q) * 384 + n * 8;   // (kq)*48*8 + xi*8
#pragma unroll
            for (int p = 0; p < 2; ++p) {
                const ushort* Ab = A0 + p * 6144 + kofs;
                const ushort* Bb = B0 + p * 6144 + kofs;
                short8 af0 = *(const short8*)(Ab);
                short8 af1 = *(const short8*)(Ab + 128);   // +16 xi
                short8 af2 = *(const short8*)(Ab + 256);   // +32 xi
                short8 bf0 = *(const short8*)(Bb);
                short8 bf1 = *(const short8*)(Bb + 128);
                short8 bf2 = *(const short8*)(Bb + 256);
                acc[p*7+0] = __builtin_amdgcn_mfma_f32_16x16x32_bf16(af0, bf0, acc[p*7+0], 0, 0, 0);
                acc[p*7+1] = __builtin_amdgcn_mfma_f32_16x16x32_bf16(af0, bf1, acc[p*7+1], 0, 0, 0);
                acc[p*7+2] = __builtin_amdgcn_mfma_f32_16x16x32_bf16(af1, bf0, acc[p*7+2], 0, 0, 0);
                acc[p*7+3] = __builtin_amdgcn_mfma_f32_16x16x32_bf16(af1, bf1, acc[p*7+3], 0, 0, 0);
                acc[p*7+4] = __builtin_amdgcn_mfma_f32_16x16x32_bf16(af1, bf2, acc[p*7+4], 0, 0, 0);
                acc[p*7+5] = __builtin_amdgcn_mfma_f32_16x16x32_bf16(af2, bf1, acc[p*7+5], 0, 0, 0);
                acc[p*7+6] = __builtin_amdgcn_mfma_f32_16x16x32_bf16(af2, bf2, acc[p*7+6], 0, 0, 0);
            }
        }
    }

    // ---- epilogue: C-tiles -> per-wave LDS [d][x] -> coalesced stores ----
    float* wl = lds + w * (ND * 100);
    {
        float4 z = make_float4(0.f, 0.f, 0.f, 0.f);
        for (int k = lane; k < (ND * 100) / 4; k += 64) ((float4*)wl)[k] = z;
    }
#pragma unroll
    for (int p = 0; p < 2; ++p) {
#pragma unroll
        for (int i = 0; i < 7; ++i) {
            const int t = TS_t[i], s = TS_s[i];
#pragma unroll
            for (int r = 0; r < 4; ++r) {
                // D[m][n]: row m = q*4+r, col = n  (m89/m91-verified mapping)
                int m = q * 4 + r;
                int d = 16 * s + n - 16 * t - m + 10;   // dxi
                int x = 2 * (16 * t + m) + p;
                if (0 <= d && d <= 20)
                    wl[d * 100 + x] = acc[p * 7 + i][r];
            }
        }
    }
    // same-wave LDS RAW: compiler inserts lgkmcnt waits; no barrier needed.
    const int base0 = ((b * (ND * ND) + dyi * ND) * HH + y) * WW;
#pragma unroll
    for (int i = 0; i < 8; ++i) {
        int fl = i * 64 + lane;               // float4 index, 21*24 = 504 total
        if (fl < 504) {
            int d  = fl / 24;
            int xi = fl % 24;
            float4 v = *(const float4*)(wl + d * 100 + xi * 4);
            *(float4*)(out + base0 + d * (HH * WW) + xi * 4) = v;
        }
    }
}

// ---------------- fallback (R3 VALU kernel) if ws too small ------------------
#define TY 8
#define CCH 4
#define NCHUNK (CC_ALL / CCH)
#define GX 4
#define NTHR 192
#define L1P 52
#define L1U (2 * L1P)
#define W2P 68
#define L2U (2 * W2P)

__global__ __launch_bounds__(NTHR, 2)
void corr_kernel(const float* __restrict__ in1,
                 const float* __restrict__ in2,
                 float* __restrict__ out) {
    __shared__ float lds1[CCH * TY * L1U];
    __shared__ float lds2[CCH * TY * L2U];
    const int tid = threadIdx.x;
    const int y0  = blockIdx.x * TY;
    const int dyi = blockIdx.y;
    const int b   = blockIdx.z;
    const int dy  = 2 * (dyi - 10);
    const int r   = tid / 24;
    const int un_ = tid % 24;
    const int p   = un_ / 12;
    const int u0  = (un_ % 12) * GX;
    float acc[ND * GX];
#pragma unroll
    for (int i = 0; i < ND * GX; ++i) acc[i] = 0.f;
    const float* in1b = in1 + b * (CC_ALL * HH * WW);
    const float* in2b = in2 + b * (CC_ALL * HH * WW);
    {
        float4 z = make_float4(0.f, 0.f, 0.f, 0.f);
        for (int k = tid; k < (CCH * TY * L2U) / 4; k += NTHR)
            ((float4*)lds2)[k] = z;
    }
    for (int ch = 0; ch < NCHUNK; ++ch) {
        const int c0 = ch * CCH;
        __syncthreads();
#pragma unroll
        for (int k = 0; k < 4; ++k) {
            int f  = tid + k * NTHR;
            int x4 = f % 24;
            int rc = f / 24;
            int c  = rc >> 3, rr = rc & 7;
            const float4 g = *(const float4*)&in1b[(c0 + c) * (HH * WW) + (y0 + rr) * WW + x4 * 4];
            float* base = &lds1[(c * TY + rr) * L1U];
            *(float2*)&base[      2 * x4] = make_float2(g.x, g.z);
            *(float2*)&base[L1P + 2 * x4] = make_float2(g.y, g.w);
        }
#pragma unroll
        for (int k = 0; k < 4; ++k) {
            int f  = tid + k * NTHR;
            int x4 = f % 24;
            int rc = f / 24;
            int c  = rc >> 3, rr = rc & 7;
            int Y  = y0 + rr + dy;
            if ((unsigned)Y < HH) {
                const float4 g = *(const float4*)&in2b[(c0 + c) * (HH * WW) + Y * WW + x4 * 4];
                float* base = &lds2[(c * TY + rr) * L2U];
                *(float2*)&base[      2 * x4 + 10] = make_float2(g.x, g.z);
                *(float2*)&base[W2P + 2 * x4 + 10] = make_float2(g.y, g.w);
            }
        }
        __syncthreads();
#pragma unroll
        for (int c = 0; c < CCH; ++c) {
            const float* a4  = &lds1[(c * TY + r) * L1U + p * L1P + u0];
            const float* v24 = &lds2[(c * TY + r) * L2U + p * W2P + u0];
            float4 af = *(const float4*)a4;
            float v[24];
#pragma unroll
            for (int m = 0; m < 24; m += 4) {
                float4 t = *(const float4*)&v24[m];
                v[m] = t.x; v[m + 1] = t.y; v[m + 2] = t.z; v[m + 3] = t.w;
            }
#pragma unroll
            for (int id = 0; id < ND; ++id) {
                acc[id * GX + 0] += af.x * v[id + 0];
                acc[id * GX + 1] += af.y * v[id + 1];
                acc[id * GX + 2] += af.z * v[id + 2];
                acc[id * GX + 3] += af.w * v[id + 3];
            }
        }
    }
    const float scale = 1.0f / 128.0f;
#pragma unroll
    for (int id = 0; id < ND; ++id) {
        int d = dyi * ND + id;
        int base = ((b * (ND * ND) + d) * HH + (y0 + r)) * WW;
#pragma unroll
        for (int j = 0; j < GX; ++j) {
            int x = 2 * (u0 + j) + p;
            out[base + x] = acc[id * GX + j] * scale;
        }
    }
}

extern "C" void kernel_launch(void* const* d_in, const int* in_sizes, int n_in,
                              void* d_out, int out_size, void* d_ws, size_t ws_size,
                              hipStream_t stream) {
    const float* in1 = (const float*)d_in[0];
    const float* in2 = (const float*)d_in[1];
    float* out = (float*)d_out;
    const size_t elems = (size_t)BB * CC_ALL * HH * WW;      // 4,718,592 per tensor
    const size_t need  = 2 * elems * sizeof(ushort);         // 18,874,368 B

    if (ws_size >= need) {
        ushort* T1 = (ushort*)d_ws;
        ushort* T2 = T1 + elems;
        dim3 tg(147456 / 256, 2);   // 576 blocks x {in1, in2}
        hipLaunchKernelGGL(transpose_cvt2, tg, dim3(256), 0, stream, in1, in2, T1, T2);
        dim3 grid(HH / 4, ND, BB);
        hipLaunchKernelGGL(corr_mfma, grid, dim3(256), 0, stream, T1, T2, out);
    } else {
        dim3 grid(HH / TY, ND, BB);
        hipLaunchKernelGGL(corr_kernel, grid, dim3(NTHR), 0, stream, in1, in2, out);
    }
}

// Round 6
// 119.840 us; speedup vs baseline: 7.3655x; 1.0209x over previous
//
#include <hip/hip_runtime.h>

// FlowNetC correlation on MI355X (round 6): MFMA banded-correlation.
// out[b, dyi*21+dxi, y, x] = (1/128) * sum_c in1[b,c,y,x] * in2[b,c,y+dy,x+dx]
//   dy = 2*(dyi-10), dx = 2*(dxi-10); in2 zero outside [0,96)^2.
//
// Parity split x = 2*xi + p  =>  out[xi, dxi] = sum_c A[xi,c] * B[xi+dxi-10, c]
// = width-21 band of A·B^T per (b, y, dy, p). Tiled 16x16x32 bf16 MFMA.
//
// R6 vs R5 (122 us; corr_mfma est. ~45 us vs ~20 us floor):
//  - XCD-aware block swizzle: 1-D grid of 2016, decode so XCD k=n%8 gets one
//    (b, yt-half) slice -> per-XCD frag working set 3.3 MB < 4 MB L2.
//    (Linear dispatch put all 21 dyi x 4 b on one XCD per yt%8: B-rows 12.7 MB
//    -> L3-served at ~10 TB/s. B is ~150 MB of the ~300 MB frag stream.)
//  - K-chunk loop explicitly unrolled (all 48 frag loads visible for pipelining)
// transpose_cvt2 and band/layout logic unchanged (verified R4/R5).

#define BB 4
#define CC_ALL 128
#define HH 96
#define WW 96
#define ND 21

typedef __attribute__((ext_vector_type(8))) short short8;
typedef __attribute__((ext_vector_type(4))) float floatx4;

__device__ __forceinline__ ushort f2bf(float f) {
    unsigned u = __builtin_bit_cast(unsigned, f);
    return (ushort)((u + 0x7FFFu + ((u >> 16) & 1u)) >> 16);
}

// ---- pre-pass (fused): f32 [b][c][y][x] -> bf16 [b][y][p][kq(16)][xi(48)][8c]
// blockIdx.y selects tensor (0: in1, scaled by 1/128; 1: in2).
__global__ __launch_bounds__(256)
void transpose_cvt2(const float* __restrict__ in1, const float* __restrict__ in2,
                    ushort* __restrict__ T1, ushort* __restrict__ T2) {
    const int sel = blockIdx.y;
    const float* __restrict__ src = sel ? in2 : in1;
    ushort* __restrict__ dst = sel ? T2 : T1;
    const float mul = sel ? 1.0f : (1.0f / 128.0f);

    int g  = blockIdx.x * 256 + threadIdx.x;   // < 4*96*16*24 = 147456
    int t  = g % 24;
    int t1 = g / 24;
    int kq = t1 % 16;
    int t2 = t1 / 16;
    int y  = t2 % 96;
    int b  = t2 / 96;

    const float* s = src + (((b * CC_ALL + kq * 8) * HH + y) * WW) + 4 * t;
    ushort e0[8], e1[8], o0[8], o1[8];      // xi = 2t and 2t+1
#pragma unroll
    for (int j = 0; j < 8; ++j) {
        float4 f = *(const float4*)(s + j * (HH * WW));
        e0[j] = f2bf(f.x * mul);
        o0[j] = f2bf(f.y * mul);
        e1[j] = f2bf(f.z * mul);
        o1[j] = f2bf(f.w * mul);
    }
    int base = (((b * 96 + y) * 2 + 0) * 16 + kq) * 48 + 2 * t;
    uint4 w;
    ushort* d0 = dst + base * 8;                 // parity 0
    w.x = e0[0] | ((unsigned)e0[1] << 16); w.y = e0[2] | ((unsigned)e0[3] << 16);
    w.z = e0[4] | ((unsigned)e0[5] << 16); w.w = e0[6] | ((unsigned)e0[7] << 16);
    *(uint4*)(d0) = w;
    w.x = e1[0] | ((unsigned)e1[1] << 16); w.y = e1[2] | ((unsigned)e1[3] << 16);
    w.z = e1[4] | ((unsigned)e1[5] << 16); w.w = e1[6] | ((unsigned)e1[7] << 16);
    *(uint4*)(d0 + 8) = w;
    ushort* d1 = d0 + 16 * 48 * 8;               // parity 1 (+6144 ushorts)
    w.x = o0[0] | ((unsigned)o0[1] << 16); w.y = o0[2] | ((unsigned)o0[3] << 16);
    w.z = o0[4] | ((unsigned)o0[5] << 16); w.w = o0[6] | ((unsigned)o0[7] << 16);
    *(uint4*)(d1) = w;
    w.x = o1[0] | ((unsigned)o1[1] << 16); w.y = o1[2] | ((unsigned)o1[3] << 16);
    w.z = o1[4] | ((unsigned)o1[5] << 16); w.w = o1[6] | ((unsigned)o1[7] << 16);
    *(uint4*)(d1 + 8) = w;
}

// ---------------- main: banded MFMA correlation ------------------------------
// 1-D grid 2016, XCD-aware decode: k = n%8 -> (b = k>>1, half = k&1);
// j = n>>3 -> (yt = half*12 + j%12, dyi = j/12). Block = 4 waves, wave = row.
// Scale 1/128 pre-folded into T1.
__global__ __launch_bounds__(256)
void corr_mfma(const ushort* __restrict__ T1, const ushort* __restrict__ T2,
               float* __restrict__ out) {
    __shared__ float lds[4 * ND * 100];   // per-wave [21 d][96 x (+4 pad)]

    const int n_   = blockIdx.x;
    const int k    = n_ & 7;
    const int j    = n_ >> 3;
    const int b    = k >> 1;
    const int half = k & 1;
    const int yt   = half * 12 + (j % 12);
    const int dyi  = j / 12;

    const int tid  = threadIdx.x;
    const int w    = tid >> 6;
    const int lane = tid & 63;
    const int nn   = lane & 15;           // N index / A's M index
    const int q    = lane >> 4;           // quad
    const int y    = yt * 4 + w;
    const int dy   = 2 * (dyi - 10);
    const int Y2   = y + dy;
    const bool rowok = (unsigned)Y2 < (unsigned)HH;

    // 7 (M-tile, N-tile) band pairs per parity
    const int TS_t[7] = {0, 0, 1, 1, 1, 2, 2};
    const int TS_s[7] = {0, 1, 0, 1, 2, 1, 2};

    floatx4 acc[14];
#pragma unroll
    for (int i = 0; i < 14; ++i) acc[i] = (floatx4)(0.0f);

    // per-(b,y,p) block = 16*48*8 = 6144 ushorts
    const ushort* A0 = T1 + ((b * 96 + y) * 2) * 6144;

    if (rowok) {
        const ushort* B0 = T2 + ((b * 96 + Y2) * 2) * 6144;
#pragma unroll
        for (int ch = 0; ch < 4; ++ch) {          // K chunks of 32 channels
            const int kofs = (4 * ch + q) * 384 + nn * 8;  // (kq)*48*8 + xi*8
#pragma unroll
            for (int p = 0; p < 2; ++p) {
                const ushort* Ab = A0 + p * 6144 + kofs;
                const ushort* Bb = B0 + p * 6144 + kofs;
                short8 af0 = *(const short8*)(Ab);
                short8 af1 = *(const short8*)(Ab + 128);   // +16 xi
                short8 af2 = *(const short8*)(Ab + 256);   // +32 xi
                short8 bf0 = *(const short8*)(Bb);
                short8 bf1 = *(const short8*)(Bb + 128);
                short8 bf2 = *(const short8*)(Bb + 256);
                acc[p*7+0] = __builtin_amdgcn_mfma_f32_16x16x32_bf16(af0, bf0, acc[p*7+0], 0, 0, 0);
                acc[p*7+1] = __builtin_amdgcn_mfma_f32_16x16x32_bf16(af0, bf1, acc[p*7+1], 0, 0, 0);
                acc[p*7+2] = __builtin_amdgcn_mfma_f32_16x16x32_bf16(af1, bf0, acc[p*7+2], 0, 0, 0);
                acc[p*7+3] = __builtin_amdgcn_mfma_f32_16x16x32_bf16(af1, bf1, acc[p*7+3], 0, 0, 0);
                acc[p*7+4] = __builtin_amdgcn_mfma_f32_16x16x32_bf16(af1, bf2, acc[p*7+4], 0, 0, 0);
                acc[p*7+5] = __builtin_amdgcn_mfma_f32_16x16x32_bf16(af2, bf1, acc[p*7+5], 0, 0, 0);
                acc[p*7+6] = __builtin_amdgcn_mfma_f32_16x16x32_bf16(af2, bf2, acc[p*7+6], 0, 0, 0);
            }
        }
    }

    // ---- epilogue: C-tiles -> per-wave LDS [d][x] -> coalesced stores ----
    float* wl = lds + w * (ND * 100);
    {
        float4 z = make_float4(0.f, 0.f, 0.f, 0.f);
        for (int kk = lane; kk < (ND * 100) / 4; kk += 64) ((float4*)wl)[kk] = z;
    }
#pragma unroll
    for (int p = 0; p < 2; ++p) {
#pragma unroll
        for (int i = 0; i < 7; ++i) {
            const int t = TS_t[i], s = TS_s[i];
#pragma unroll
            for (int r = 0; r < 4; ++r) {
                // D[m][n]: row m = q*4+r, col = nn  (m89/m91-verified mapping)
                int m = q * 4 + r;
                int d = 16 * s + nn - 16 * t - m + 10;   // dxi
                int x = 2 * (16 * t + m) + p;
                if (0 <= d && d <= 20)
                    wl[d * 100 + x] = acc[p * 7 + i][r];
            }
        }
    }
    // same-wave LDS RAW: compiler inserts lgkmcnt waits; no barrier needed.
    const int base0 = ((b * (ND * ND) + dyi * ND) * HH + y) * WW;
#pragma unroll
    for (int i = 0; i < 8; ++i) {
        int fl = i * 64 + lane;               // float4 index, 21*24 = 504 total
        if (fl < 504) {
            int d  = fl / 24;
            int xi = fl % 24;
            float4 v = *(const float4*)(wl + d * 100 + xi * 4);
            *(float4*)(out + base0 + d * (HH * WW) + xi * 4) = v;
        }
    }
}

// ---------------- fallback (R3 VALU kernel) if ws too small ------------------
#define TY 8
#define CCH 4
#define NCHUNK (CC_ALL / CCH)
#define GX 4
#define NTHR 192
#define L1P 52
#define L1U (2 * L1P)
#define W2P 68
#define L2U (2 * W2P)

__global__ __launch_bounds__(NTHR, 2)
void corr_kernel(const float* __restrict__ in1,
                 const float* __restrict__ in2,
                 float* __restrict__ out) {
    __shared__ float lds1[CCH * TY * L1U];
    __shared__ float lds2[CCH * TY * L2U];
    const int tid = threadIdx.x;
    const int y0  = blockIdx.x * TY;
    const int dyi = blockIdx.y;
    const int b   = blockIdx.z;
    const int dy  = 2 * (dyi - 10);
    const int r   = tid / 24;
    const int un_ = tid % 24;
    const int p   = un_ / 12;
    const int u0  = (un_ % 12) * GX;
    float acc[ND * GX];
#pragma unroll
    for (int i = 0; i < ND * GX; ++i) acc[i] = 0.f;
    const float* in1b = in1 + b * (CC_ALL * HH * WW);
    const float* in2b = in2 + b * (CC_ALL * HH * WW);
    {
        float4 z = make_float4(0.f, 0.f, 0.f, 0.f);
        for (int k = tid; k < (CCH * TY * L2U) / 4; k += NTHR)
            ((float4*)lds2)[k] = z;
    }
    for (int ch = 0; ch < NCHUNK; ++ch) {
        const int c0 = ch * CCH;
        __syncthreads();
#pragma unroll
        for (int k = 0; k < 4; ++k) {
            int f  = tid + k * NTHR;
            int x4 = f % 24;
            int rc = f / 24;
            int c  = rc >> 3, rr = rc & 7;
            const float4 g = *(const float4*)&in1b[(c0 + c) * (HH * WW) + (y0 + rr) * WW + x4 * 4];
            float* base = &lds1[(c * TY + rr) * L1U];
            *(float2*)&base[      2 * x4] = make_float2(g.x, g.z);
            *(float2*)&base[L1P + 2 * x4] = make_float2(g.y, g.w);
        }
#pragma unroll
        for (int k = 0; k < 4; ++k) {
            int f  = tid + k * NTHR;
            int x4 = f % 24;
            int rc = f / 24;
            int c  = rc >> 3, rr = rc & 7;
            int Y  = y0 + rr + dy;
            if ((unsigned)Y < HH) {
                const float4 g = *(const float4*)&in2b[(c0 + c) * (HH * WW) + Y * WW + x4 * 4];
                float* base = &lds2[(c * TY + rr) * L2U];
                *(float2*)&base[      2 * x4 + 10] = make_float2(g.x, g.z);
                *(float2*)&base[W2P + 2 * x4 + 10] = make_float2(g.y, g.w);
            }
        }
        __syncthreads();
#pragma unroll
        for (int c = 0; c < CCH; ++c) {
            const float* a4  = &lds1[(c * TY + r) * L1U + p * L1P + u0];
            const float* v24 = &lds2[(c * TY + r) * L2U + p * W2P + u0];
            float4 af = *(const float4*)a4;
            float v[24];
#pragma unroll
            for (int m = 0; m < 24; m += 4) {
                float4 t = *(const float4*)&v24[m];
                v[m] = t.x; v[m + 1] = t.y; v[m + 2] = t.z; v[m + 3] = t.w;
            }
#pragma unroll
            for (int id = 0; id < ND; ++id) {
                acc[id * GX + 0] += af.x * v[id + 0];
                acc[id * GX + 1] += af.y * v[id + 1];
                acc[id * GX + 2] += af.z * v[id + 2];
                acc[id * GX + 3] += af.w * v[id + 3];
            }
        }
    }
    const float scale = 1.0f / 128.0f;
#pragma unroll
    for (int id = 0; id < ND; ++id) {
        int d = dyi * ND + id;
        int base = ((b * (ND * ND) + d) * HH + (y0 + r)) * WW;
#pragma unroll
        for (int j = 0; j < GX; ++j) {
            int x = 2 * (u0 + j) + p;
            out[base + x] = acc[id * GX + j] * scale;
        }
    }
}

extern "C" void kernel_launch(void* const* d_in, const int* in_sizes, int n_in,
                              void* d_out, int out_size, void* d_ws, size_t ws_size,
                              hipStream_t stream) {
    const float* in1 = (const float*)d_in[0];
    const float* in2 = (const float*)d_in[1];
    float* out = (float*)d_out;
    const size_t elems = (size_t)BB * CC_ALL * HH * WW;      // 4,718,592 per tensor
    const size_t need  = 2 * elems * sizeof(ushort);         // 18,874,368 B

    if (ws_size >= need) {
        ushort* T1 = (ushort*)d_ws;
        ushort* T2 = T1 + elems;
        dim3 tg(147456 / 256, 2);   // 576 blocks x {in1, in2}
        hipLaunchKernelGGL(transpose_cvt2, tg, dim3(256), 0, stream, in1, in2, T1, T2);
        hipLaunchKernelGGL(corr_mfma, dim3(2016), dim3(256), 0, stream, T1, T2, out);
    } else {
        dim3 grid(HH / TY, ND, BB);
        hipLaunchKernelGGL(corr_kernel, grid, dim3(NTHR), 0, stream, in1, in2, out);
    }
}

// Round 7
// 119.631 us; speedup vs baseline: 7.3784x; 1.0018x over previous
//
#include <hip/hip_runtime.h>

// FlowNetC correlation on MI355X (round 7): MFMA banded-correlation.
// out[b, dyi*21+dxi, y, x] = (1/128) * sum_c in1[b,c,y,x] * in2[b,c,y+dy,x+dx]
//   dy = 2*(dyi-10), dx = 2*(dxi-10); in2 zero outside [0,96)^2.
//
// Parity split x = 2*xi + p  =>  out[xi, dxi] = sum_c A[xi,c] * B[xi+dxi-10, c]
// = width-21 band of A·B^T per (b, y, dy, p). Tiled 16x16x32 bf16 MFMA.
//
// R7 vs R6 (119.8 us): epilogue scatter was 8-way bank-conflicted:
//   old addr = C + 4*nn - 392*q (mod 32) -> 64 lanes on 8 banks (2.94x, m136).
// Fix: SWAP the MFMA operands (bf as operand 1). D rows m then index in2-x,
// cols nn index in1-x; scatter addr = C + 400*q - 98*nn (mod 32) -> 16 even
// banks x 4 lanes = 4-way (1.58x ~ free). Same loads, same band pairs, same
// coalesced b128 read-back. Scatter also skipped when rowok==false.

#define BB 4
#define CC_ALL 128
#define HH 96
#define WW 96
#define ND 21

typedef __attribute__((ext_vector_type(8))) short short8;
typedef __attribute__((ext_vector_type(4))) float floatx4;

__device__ __forceinline__ ushort f2bf(float f) {
    unsigned u = __builtin_bit_cast(unsigned, f);
    return (ushort)((u + 0x7FFFu + ((u >> 16) & 1u)) >> 16);
}

// ---- pre-pass (fused): f32 [b][c][y][x] -> bf16 [b][y][p][kq(16)][xi(48)][8c]
// blockIdx.y selects tensor (0: in1, scaled by 1/128; 1: in2).
__global__ __launch_bounds__(256)
void transpose_cvt2(const float* __restrict__ in1, const float* __restrict__ in2,
                    ushort* __restrict__ T1, ushort* __restrict__ T2) {
    const int sel = blockIdx.y;
    const float* __restrict__ src = sel ? in2 : in1;
    ushort* __restrict__ dst = sel ? T2 : T1;
    const float mul = sel ? 1.0f : (1.0f / 128.0f);

    int g  = blockIdx.x * 256 + threadIdx.x;   // < 4*96*16*24 = 147456
    int t  = g % 24;
    int t1 = g / 24;
    int kq = t1 % 16;
    int t2 = t1 / 16;
    int y  = t2 % 96;
    int b  = t2 / 96;

    const float* s = src + (((b * CC_ALL + kq * 8) * HH + y) * WW) + 4 * t;
    ushort e0[8], e1[8], o0[8], o1[8];      // xi = 2t and 2t+1
#pragma unroll
    for (int j = 0; j < 8; ++j) {
        float4 f = *(const float4*)(s + j * (HH * WW));
        e0[j] = f2bf(f.x * mul);
        o0[j] = f2bf(f.y * mul);
        e1[j] = f2bf(f.z * mul);
        o1[j] = f2bf(f.w * mul);
    }
    int base = (((b * 96 + y) * 2 + 0) * 16 + kq) * 48 + 2 * t;
    uint4 w;
    ushort* d0 = dst + base * 8;                 // parity 0
    w.x = e0[0] | ((unsigned)e0[1] << 16); w.y = e0[2] | ((unsigned)e0[3] << 16);
    w.z = e0[4] | ((unsigned)e0[5] << 16); w.w = e0[6] | ((unsigned)e0[7] << 16);
    *(uint4*)(d0) = w;
    w.x = e1[0] | ((unsigned)e1[1] << 16); w.y = e1[2] | ((unsigned)e1[3] << 16);
    w.z = e1[4] | ((unsigned)e1[5] << 16); w.w = e1[6] | ((unsigned)e1[7] << 16);
    *(uint4*)(d0 + 8) = w;
    ushort* d1 = d0 + 16 * 48 * 8;               // parity 1 (+6144 ushorts)
    w.x = o0[0] | ((unsigned)o0[1] << 16); w.y = o0[2] | ((unsigned)o0[3] << 16);
    w.z = o0[4] | ((unsigned)o0[5] << 16); w.w = o0[6] | ((unsigned)o0[7] << 16);
    *(uint4*)(d1) = w;
    w.x = o1[0] | ((unsigned)o1[1] << 16); w.y = o1[2] | ((unsigned)o1[3] << 16);
    w.z = o1[4] | ((unsigned)o1[5] << 16); w.w = o1[6] | ((unsigned)o1[7] << 16);
    *(uint4*)(d1 + 8) = w;
}

// ---------------- main: banded MFMA correlation ------------------------------
// 1-D grid 2016, XCD-aware decode: k = n%8 -> (b = k>>1, half = k&1);
// j = n>>3 -> (yt = half*12 + j%12, dyi = j/12). Block = 4 waves, wave = row.
// Scale 1/128 pre-folded into T1. MFMA operand order: (bf, af) — see header.
__global__ __launch_bounds__(256)
void corr_mfma(const ushort* __restrict__ T1, const ushort* __restrict__ T2,
               float* __restrict__ out) {
    __shared__ float lds[4 * ND * 100];   // per-wave [21 d][96 x (+4 pad)]

    const int n_   = blockIdx.x;
    const int k    = n_ & 7;
    const int j    = n_ >> 3;
    const int b    = k >> 1;
    const int half = k & 1;
    const int yt   = half * 12 + (j % 12);
    const int dyi  = j / 12;

    const int tid  = threadIdx.x;
    const int w    = tid >> 6;
    const int lane = tid & 63;
    const int nn   = lane & 15;           // col index of D = in1-x tile-local
    const int q    = lane >> 4;           // quad; D row m = q*4 + r = in2-x local
    const int y    = yt * 4 + w;
    const int dy   = 2 * (dyi - 10);
    const int Y2   = y + dy;
    const bool rowok = (unsigned)Y2 < (unsigned)HH;

    // 7 (t = in1 M-tile, s = in2 N-tile) band pairs per parity
    const int TS_t[7] = {0, 0, 1, 1, 1, 2, 2};
    const int TS_s[7] = {0, 1, 0, 1, 2, 1, 2};

    floatx4 acc[14];
#pragma unroll
    for (int i = 0; i < 14; ++i) acc[i] = (floatx4)(0.0f);

    // per-(b,y,p) block = 16*48*8 = 6144 ushorts
    const ushort* A0 = T1 + ((b * 96 + y) * 2) * 6144;

    if (rowok) {
        const ushort* B0 = T2 + ((b * 96 + Y2) * 2) * 6144;
#pragma unroll
        for (int ch = 0; ch < 4; ++ch) {          // K chunks of 32 channels
            const int kofs = (4 * ch + q) * 384 + nn * 8;  // (kq)*48*8 + xi*8
#pragma unroll
            for (int p = 0; p < 2; ++p) {
                const ushort* Ab = A0 + p * 6144 + kofs;
                const ushort* Bb = B0 + p * 6144 + kofs;
                short8 af0 = *(const short8*)(Ab);
                short8 af1 = *(const short8*)(Ab + 128);   // +16 xi
                short8 af2 = *(const short8*)(Ab + 256);   // +32 xi
                short8 bf0 = *(const short8*)(Bb);
                short8 bf1 = *(const short8*)(Bb + 128);
                short8 bf2 = *(const short8*)(Bb + 256);
                // operand order (bf, af): D rows = in2-x, cols = in1-x
                acc[p*7+0] = __builtin_amdgcn_mfma_f32_16x16x32_bf16(bf0, af0, acc[p*7+0], 0, 0, 0);
                acc[p*7+1] = __builtin_amdgcn_mfma_f32_16x16x32_bf16(bf1, af0, acc[p*7+1], 0, 0, 0);
                acc[p*7+2] = __builtin_amdgcn_mfma_f32_16x16x32_bf16(bf0, af1, acc[p*7+2], 0, 0, 0);
                acc[p*7+3] = __builtin_amdgcn_mfma_f32_16x16x32_bf16(bf1, af1, acc[p*7+3], 0, 0, 0);
                acc[p*7+4] = __builtin_amdgcn_mfma_f32_16x16x32_bf16(bf2, af1, acc[p*7+4], 0, 0, 0);
                acc[p*7+5] = __builtin_amdgcn_mfma_f32_16x16x32_bf16(bf1, af2, acc[p*7+5], 0, 0, 0);
                acc[p*7+6] = __builtin_amdgcn_mfma_f32_16x16x32_bf16(bf2, af2, acc[p*7+6], 0, 0, 0);
            }
        }
    }

    // ---- epilogue: C-tiles -> per-wave LDS [d][x] -> coalesced stores ----
    float* wl = lds + w * (ND * 100);
    {
        float4 z = make_float4(0.f, 0.f, 0.f, 0.f);
        for (int kk = lane; kk < (ND * 100) / 4; kk += 64) ((float4*)wl)[kk] = z;
    }
    if (rowok) {
#pragma unroll
        for (int p = 0; p < 2; ++p) {
#pragma unroll
            for (int i = 0; i < 7; ++i) {
                const int t = TS_t[i], s = TS_s[i];
#pragma unroll
                for (int r = 0; r < 4; ++r) {
                    // D[m][nn]: row m = q*4+r (in2-local), col = nn (in1-local)
                    int m = q * 4 + r;
                    int d = 16 * s + m - 16 * t - nn + 10;   // dxi
                    int x = 2 * (16 * t + nn) + p;
                    if (0 <= d && d <= 20)
                        wl[d * 100 + x] = acc[p * 7 + i][r];
                }
            }
        }
    }
    // same-wave LDS RAW: compiler inserts lgkmcnt waits; no barrier needed.
    const int base0 = ((b * (ND * ND) + dyi * ND) * HH + y) * WW;
#pragma unroll
    for (int i = 0; i < 8; ++i) {
        int fl = i * 64 + lane;               // float4 index, 21*24 = 504 total
        if (fl < 504) {
            int d  = fl / 24;
            int xi = fl % 24;
            float4 v = *(const float4*)(wl + d * 100 + xi * 4);
            *(float4*)(out + base0 + d * (HH * WW) + xi * 4) = v;
        }
    }
}

// ---------------- fallback (R3 VALU kernel) if ws too small ------------------
#define TY 8
#define CCH 4
#define NCHUNK (CC_ALL / CCH)
#define GX 4
#define NTHR 192
#define L1P 52
#define L1U (2 * L1P)
#define W2P 68
#define L2U (2 * W2P)

__global__ __launch_bounds__(NTHR, 2)
void corr_kernel(const float* __restrict__ in1,
                 const float* __restrict__ in2,
                 float* __restrict__ out) {
    __shared__ float lds1[CCH * TY * L1U];
    __shared__ float lds2[CCH * TY * L2U];
    const int tid = threadIdx.x;
    const int y0  = blockIdx.x * TY;
    const int dyi = blockIdx.y;
    const int b   = blockIdx.z;
    const int dy  = 2 * (dyi - 10);
    const int r   = tid / 24;
    const int un_ = tid % 24;
    const int p   = un_ / 12;
    const int u0  = (un_ % 12) * GX;
    float acc[ND * GX];
#pragma unroll
    for (int i = 0; i < ND * GX; ++i) acc[i] = 0.f;
    const float* in1b = in1 + b * (CC_ALL * HH * WW);
    const float* in2b = in2 + b * (CC_ALL * HH * WW);
    {
        float4 z = make_float4(0.f, 0.f, 0.f, 0.f);
        for (int k = tid; k < (CCH * TY * L2U) / 4; k += NTHR)
            ((float4*)lds2)[k] = z;
    }
    for (int ch = 0; ch < NCHUNK; ++ch) {
        const int c0 = ch * CCH;
        __syncthreads();
#pragma unroll
        for (int k = 0; k < 4; ++k) {
            int f  = tid + k * NTHR;
            int x4 = f % 24;
            int rc = f / 24;
            int c  = rc >> 3, rr = rc & 7;
            const float4 g = *(const float4*)&in1b[(c0 + c) * (HH * WW) + (y0 + rr) * WW + x4 * 4];
            float* base = &lds1[(c * TY + rr) * L1U];
            *(float2*)&base[      2 * x4] = make_float2(g.x, g.z);
            *(float2*)&base[L1P + 2 * x4] = make_float2(g.y, g.w);
        }
#pragma unroll
        for (int k = 0; k < 4; ++k) {
            int f  = tid + k * NTHR;
            int x4 = f % 24;
            int rc = f / 24;
            int c  = rc >> 3, rr = rc & 7;
            int Y  = y0 + rr + dy;
            if ((unsigned)Y < HH) {
                const float4 g = *(const float4*)&in2b[(c0 + c) * (HH * WW) + Y * WW + x4 * 4];
                float* base = &lds2[(c * TY + rr) * L2U];
                *(float2*)&base[      2 * x4 + 10] = make_float2(g.x, g.z);
                *(float2*)&base[W2P + 2 * x4 + 10] = make_float2(g.y, g.w);
            }
        }
        __syncthreads();
#pragma unroll
        for (int c = 0; c < CCH; ++c) {
            const float* a4  = &lds1[(c * TY + r) * L1U + p * L1P + u0];
            const float* v24 = &lds2[(c * TY + r) * L2U + p * W2P + u0];
            float4 af = *(const float4*)a4;
            float v[24];
#pragma unroll
            for (int m = 0; m < 24; m += 4) {
                float4 t = *(const float4*)&v24[m];
                v[m] = t.x; v[m + 1] = t.y; v[m + 2] = t.z; v[m + 3] = t.w;
            }
#pragma unroll
            for (int id = 0; id < ND; ++id) {
                acc[id * GX + 0] += af.x * v[id + 0];
                acc[id * GX + 1] += af.y * v[id + 1];
                acc[id * GX + 2] += af.z * v[id + 2];
                acc[id * GX + 3] += af.w * v[id + 3];
            }
        }
    }
    const float scale = 1.0f / 128.0f;
#pragma unroll
    for (int id = 0; id < ND; ++id) {
        int d = dyi * ND + id;
        int base = ((b * (ND * ND) + d) * HH + (y0 + r)) * WW;
#pragma unroll
        for (int j = 0; j < GX; ++j) {
            int x = 2 * (u0 + j) + p;
            out[base + x] = acc[id * GX + j] * scale;
        }
    }
}

extern "C" void kernel_launch(void* const* d_in, const int* in_sizes, int n_in,
                              void* d_out, int out_size, void* d_ws, size_t ws_size,
                              hipStream_t stream) {
    const float* in1 = (const float*)d_in[0];
    const float* in2 = (const float*)d_in[1];
    float* out = (float*)d_out;
    const size_t elems = (size_t)BB * CC_ALL * HH * WW;      // 4,718,592 per tensor
    const size_t need  = 2 * elems * sizeof(ushort);         // 18,874,368 B

    if (ws_size >= need) {
        ushort* T1 = (ushort*)d_ws;
        ushort* T2 = T1 + elems;
        dim3 tg(147456 / 256, 2);   // 576 blocks x {in1, in2}
        hipLaunchKernelGGL(transpose_cvt2, tg, dim3(256), 0, stream, in1, in2, T1, T2);
        hipLaunchKernelGGL(corr_mfma, dim3(2016), dim3(256), 0, stream, T1, T2, out);
    } else {
        dim3 grid(HH / TY, ND, BB);
        hipLaunchKernelGGL(corr_kernel, grid, dim3(NTHR), 0, stream, in1, in2, out);
    }
}